// Round 1
// baseline (351.024 us; speedup 1.0000x reference)
//
#include <hip/hip_runtime.h>

#define BB    8
#define LL    2
#define DIM   1024
#define NH    8
#define HD    128
#define BS    16
#define NB    129
#define NSPLIT 16
#define SCALE 0.08838834764831845f   // 1/sqrt(128)
#define EPS   1e-5f

__device__ __forceinline__ float wave_reduce_add(float v) {
#pragma unroll
  for (int o = 32; o; o >>= 1) v += __shfl_xor(v, o);
  return v;
}

// -------------------- RMSNorm: one block per batch row --------------------
__global__ void rmsnorm_k(const float* __restrict__ x, const float* __restrict__ w,
                          float* __restrict__ out) {
  int b = blockIdx.x;
  float4 v = ((const float4*)(x + (size_t)b * DIM))[threadIdx.x];
  float s = v.x * v.x + v.y * v.y + v.z * v.z + v.w * v.w;
  s = wave_reduce_add(s);
  __shared__ float wsum[4];
  int wid = threadIdx.x >> 6;
  if ((threadIdx.x & 63) == 0) wsum[wid] = s;
  __syncthreads();
  float tot = wsum[0] + wsum[1] + wsum[2] + wsum[3];
  float r = rsqrtf(tot * (1.0f / DIM) + EPS);
  float4 wv = ((const float4*)w)[threadIdx.x];
  float4 o;
  o.x = v.x * r * wv.x; o.y = v.y * r * wv.y;
  o.z = v.z * r * wv.z; o.w = v.w * r * wv.w;
  ((float4*)(out + (size_t)b * DIM))[threadIdx.x] = o;
}

// -------------------- QKV GEMV: one wave per output row (3072 rows) --------------------
__global__ void qkv_k(const float* __restrict__ h,
                      const float* __restrict__ wq, const float* __restrict__ wk,
                      const float* __restrict__ wv,
                      float* __restrict__ q, float* __restrict__ k, float* __restrict__ v) {
  __shared__ float hs[BB * DIM];
  for (int i = threadIdx.x; i < BB * DIM / 4; i += 256)
    ((float4*)hs)[i] = ((const float4*)h)[i];
  __syncthreads();
  int wid = threadIdx.x >> 6, lane = threadIdx.x & 63;
  int row = blockIdx.x * 4 + wid;        // 0..3071
  int mat = row >> 10, r = row & 1023;
  const float* W = (mat == 0 ? wq : mat == 1 ? wk : wv) + (size_t)r * DIM;
  float acc[BB] = {};
#pragma unroll
  for (int it = 0; it < 4; ++it) {
    int j = it * 256 + lane * 4;
    float4 w4 = *(const float4*)(W + j);
#pragma unroll
    for (int bb = 0; bb < BB; ++bb) {
      float4 h4 = *(const float4*)(hs + bb * DIM + j);
      acc[bb] += w4.x * h4.x + w4.y * h4.y + w4.z * h4.z + w4.w * h4.w;
    }
  }
  float* dst = (mat == 0 ? q : mat == 1 ? k : v);
#pragma unroll
  for (int bb = 0; bb < BB; ++bb) {
    float s = wave_reduce_add(acc[bb]);
    if (lane == 0) dst[bb * DIM + r] = s;
  }
}

// -------------------- generic 1024-row GEMV (+residual) --------------------
__global__ void proj_res_k(const float* __restrict__ in, const float* __restrict__ W0,
                           const float* __restrict__ resid, float* __restrict__ out) {
  __shared__ float hs[BB * DIM];
  for (int i = threadIdx.x; i < BB * DIM / 4; i += 256)
    ((float4*)hs)[i] = ((const float4*)in)[i];
  __syncthreads();
  int wid = threadIdx.x >> 6, lane = threadIdx.x & 63;
  int r = blockIdx.x * 4 + wid;          // 0..1023
  const float* W = W0 + (size_t)r * DIM;
  float acc[BB] = {};
#pragma unroll
  for (int it = 0; it < 4; ++it) {
    int j = it * 256 + lane * 4;
    float4 w4 = *(const float4*)(W + j);
#pragma unroll
    for (int bb = 0; bb < BB; ++bb) {
      float4 h4 = *(const float4*)(hs + bb * DIM + j);
      acc[bb] += w4.x * h4.x + w4.y * h4.y + w4.z * h4.z + w4.w * h4.w;
    }
  }
#pragma unroll
  for (int bb = 0; bb < BB; ++bb) {
    float s = wave_reduce_add(acc[bb]);
    if (lane == 0) out[bb * DIM + r] = s + resid[bb * DIM + r];
  }
}

// -------------------- FFN w1/w3 + SwiGLU: one wave per row (4096 rows) --------------------
__global__ void ffn13_k(const float* __restrict__ h, const float* __restrict__ w1,
                        const float* __restrict__ w3, float* __restrict__ g) {
  __shared__ float hs[BB * DIM];
  for (int i = threadIdx.x; i < BB * DIM / 4; i += 256)
    ((float4*)hs)[i] = ((const float4*)h)[i];
  __syncthreads();
  int wid = threadIdx.x >> 6, lane = threadIdx.x & 63;
  int r = blockIdx.x * 4 + wid;          // 0..4095
  const float* W1 = w1 + (size_t)r * DIM;
  const float* W3 = w3 + (size_t)r * DIM;
  float a[BB] = {}, c[BB] = {};
#pragma unroll
  for (int it = 0; it < 4; ++it) {
    int j = it * 256 + lane * 4;
    float4 w14 = *(const float4*)(W1 + j);
    float4 w34 = *(const float4*)(W3 + j);
#pragma unroll
    for (int bb = 0; bb < BB; ++bb) {
      float4 h4 = *(const float4*)(hs + bb * DIM + j);
      a[bb] += w14.x * h4.x + w14.y * h4.y + w14.z * h4.z + w14.w * h4.w;
      c[bb] += w34.x * h4.x + w34.y * h4.y + w34.z * h4.z + w34.w * h4.w;
    }
  }
#pragma unroll
  for (int bb = 0; bb < BB; ++bb) {
    float av = wave_reduce_add(a[bb]);
    float cv = wave_reduce_add(c[bb]);
    if (lane == 0) {
      float sv = av / (1.0f + __expf(-av));   // silu
      g[bb * 4 * DIM + r] = sv * cv;
    }
  }
}

// -------------------- FFN w2 (+residual): one wave per row, K=4096 --------------------
__global__ void ffn2_k(const float* __restrict__ g, const float* __restrict__ w2,
                       const float* __restrict__ resid, float* __restrict__ out) {
  int wid = threadIdx.x >> 6, lane = threadIdx.x & 63;
  int r = blockIdx.x * 4 + wid;          // 0..1023
  const float* W = w2 + (size_t)r * 4 * DIM;
  float acc[BB] = {};
#pragma unroll
  for (int it = 0; it < 16; ++it) {
    int j = it * 256 + lane * 4;
    float4 w4 = *(const float4*)(W + j);
#pragma unroll
    for (int bb = 0; bb < BB; ++bb) {
      float4 g4 = *(const float4*)(g + bb * 4 * DIM + j);
      acc[bb] += w4.x * g4.x + w4.y * g4.y + w4.z * g4.z + w4.w * g4.w;
    }
  }
#pragma unroll
  for (int bb = 0; bb < BB; ++bb) {
    float s = wave_reduce_add(acc[bb]);
    if (lane == 0) out[bb * DIM + r] = s + resid[bb * DIM + r];
  }
}

// -------------------- flash-decode partial: grid (NSPLIT, B*H), 8 half-wave groups --------------------
__global__ void attn_partial_k(const float* __restrict__ qb, const float* __restrict__ kb,
                               const float* __restrict__ vb,
                               const float* __restrict__ kheap, const float* __restrict__ vheap,
                               const int* __restrict__ bt, const int* __restrict__ ctx_lens,
                               float* __restrict__ pm, float* __restrict__ ps,
                               float* __restrict__ pacc) {
  int c  = blockIdx.x;
  int bh = blockIdx.y;
  int b = bh >> 3, hh = bh & 7;
  int grp = threadIdx.x >> 5, lane = threadIdx.x & 31;
  int ctx = ctx_lens[b];
  int CH = (ctx + NSPLIT - 1) / NSPLIT;
  int t0 = c * CH;
  int t1 = t0 + CH; if (t1 > ctx) t1 = ctx;
  int last = ctx - 1;
  const float4 q4 = *(const float4*)(qb + (size_t)b * DIM + hh * HD + lane * 4);
  const int* btb = bt + b * NB;
  float m = -1e30f, ssum = 0.0f;
  float4 acc = make_float4(0.f, 0.f, 0.f, 0.f);
  for (int t = t0 + grp; t < t1; t += 8) {
    const float *Kp, *Vp;
    if (t == last) {
      Kp = kb + (size_t)b * DIM + hh * HD;
      Vp = vb + (size_t)b * DIM + hh * HD;
    } else {
      int pb = btb[t >> 4];
      size_t base = ((((size_t)pb * BS) + (t & 15)) * NH + hh) * HD;
      Kp = kheap + base;
      Vp = vheap + base;
    }
    float4 k4 = *(const float4*)(Kp + lane * 4);
    float sc = q4.x * k4.x + q4.y * k4.y + q4.z * k4.z + q4.w * k4.w;
#pragma unroll
    for (int o = 16; o; o >>= 1) sc += __shfl_xor(sc, o);
    sc *= SCALE;
    float mnew = fmaxf(m, sc);
    float f = __expf(m - mnew);
    float p = __expf(sc - mnew);
    float4 v4 = *(const float4*)(Vp + lane * 4);
    ssum = ssum * f + p;
    acc.x = acc.x * f + p * v4.x;
    acc.y = acc.y * f + p * v4.y;
    acc.z = acc.z * f + p * v4.z;
    acc.w = acc.w * f + p * v4.w;
    m = mnew;
  }
  int pi = bh * (NSPLIT * 8) + c * 8 + grp;
  if (lane == 0) { pm[pi] = m; ps[pi] = ssum; }
  *(float4*)(pacc + (size_t)pi * HD + lane * 4) = acc;
}

// -------------------- flash-decode reduce: one block per (b,h), 128 threads --------------------
__global__ void attn_reduce_k(const float* __restrict__ pm, const float* __restrict__ ps,
                              const float* __restrict__ pacc, float* __restrict__ ab) {
  int bh = blockIdx.x;
  int tid = threadIdx.x;   // 0..127
  __shared__ float f[128];
  __shared__ float red[128];
  float mi = pm[bh * 128 + tid];
  red[tid] = mi; __syncthreads();
#pragma unroll
  for (int o = 64; o; o >>= 1) {
    if (tid < o) red[tid] = fmaxf(red[tid], red[tid + o]);
    __syncthreads();
  }
  float M = red[0];
  __syncthreads();
  float fi = __expf(mi - M);
  f[tid] = fi;
  red[tid] = ps[bh * 128 + tid] * fi;
  __syncthreads();
#pragma unroll
  for (int o = 64; o; o >>= 1) {
    if (tid < o) red[tid] += red[tid + o];
    __syncthreads();
  }
  float inv = 1.0f / red[0];
  float od = 0.0f;
  for (int p = 0; p < 128; ++p)
    od += pacc[((size_t)bh * 128 + p) * HD + tid] * f[p];
  ab[bh * HD + tid] = od * inv;
}

extern "C" void kernel_launch(void* const* d_in, const int* in_sizes, int n_in,
                              void* d_out, int out_size, void* d_ws, size_t ws_size,
                              hipStream_t stream) {
  const float* x0    = (const float*)d_in[0];
  const float* kheap = (const float*)d_in[1];
  const float* vheap = (const float*)d_in[2];
  const int*   bt    = (const int*)d_in[3];
  // d_in[4] = slot_mapping (int64) — unused; derived from context_lens instead.
  const int*   ctx   = (const int*)d_in[5];
  const float* wq    = (const float*)d_in[6];
  const float* wk    = (const float*)d_in[7];
  const float* wv    = (const float*)d_in[8];
  const float* wo    = (const float*)d_in[9];
  const float* w1    = (const float*)d_in[10];
  const float* w2    = (const float*)d_in[11];
  const float* w3    = (const float*)d_in[12];
  const float* norm1 = (const float*)d_in[13];
  const float* norm2 = (const float*)d_in[14];
  const float* normf = (const float*)d_in[15];

  float* ws = (float*)d_ws;
  float* h    = ws;                 // 8192
  float* q    = ws + 8192;          // 8192
  float* k    = ws + 16384;         // 8192
  float* v    = ws + 24576;         // 8192
  float* g    = ws + 32768;         // 32768
  float* xa   = ws + 65536;         // 8192
  float* xf   = ws + 73728;         // 8192
  float* ab   = ws + 81920;         // 8192
  float* pm   = ws + 90112;         // 8192
  float* ps   = ws + 98304;         // 8192
  float* pacc = ws + 106496;        // 64*128*128 = 1048576

  const size_t WD = (size_t)DIM * DIM;       // 1 MiB floats
  const size_t WF = (size_t)4 * DIM * DIM;   // 4 MiB floats

  for (int l = 0; l < LL; ++l) {
    const float* xin = (l == 0) ? x0 : xf;
    rmsnorm_k<<<BB, 256, 0, stream>>>(xin, norm1 + l * DIM, h);
    qkv_k<<<768, 256, 0, stream>>>(h, wq + l * WD, wk + l * WD, wv + l * WD, q, k, v);
    attn_partial_k<<<dim3(NSPLIT, BB * NH), 256, 0, stream>>>(
        q, k, v, kheap, vheap, bt + l * BB * NB, ctx, pm, ps, pacc);
    attn_reduce_k<<<BB * NH, 128, 0, stream>>>(pm, ps, pacc, ab);
    proj_res_k<<<256, 256, 0, stream>>>(ab, wo + l * WD, xin, xa);
    rmsnorm_k<<<BB, 256, 0, stream>>>(xa, norm2 + l * DIM, h);
    ffn13_k<<<1024, 256, 0, stream>>>(h, w1 + l * WF, w3 + l * WF, g);
    ffn2_k<<<256, 256, 0, stream>>>(g, w2 + l * WF, xa, xf);
  }
  rmsnorm_k<<<BB, 256, 0, stream>>>(xf, normf, (float*)d_out);
}

// Round 2
// 182.134 us; speedup vs baseline: 1.9273x; 1.9273x over previous
//
#include <hip/hip_runtime.h>

#define BB    8
#define LL    2
#define DIM   1024
#define NH    8
#define HD    128
#define BS    16
#define NB    129
#define NSPLIT 16
#define SCALE 0.08838834764831845f   // 1/sqrt(128)
#define EPS   1e-5f

__device__ __forceinline__ float wave_reduce_add(float v) {
#pragma unroll
  for (int o = 32; o; o >>= 1) v += __shfl_xor(v, o);
  return v;
}

// -------------------- RMSNorm: one block per batch row --------------------
__global__ void rmsnorm_k(const float* __restrict__ x, const float* __restrict__ w,
                          float* __restrict__ out) {
  int b = blockIdx.x;
  float4 v = ((const float4*)(x + (size_t)b * DIM))[threadIdx.x];
  float s = v.x * v.x + v.y * v.y + v.z * v.z + v.w * v.w;
  s = wave_reduce_add(s);
  __shared__ float wsum[4];
  int wid = threadIdx.x >> 6;
  if ((threadIdx.x & 63) == 0) wsum[wid] = s;
  __syncthreads();
  float tot = wsum[0] + wsum[1] + wsum[2] + wsum[3];
  float r = rsqrtf(tot * (1.0f / DIM) + EPS);
  float4 wv = ((const float4*)w)[threadIdx.x];
  float4 o;
  o.x = v.x * r * wv.x; o.y = v.y * r * wv.y;
  o.z = v.z * r * wv.z; o.w = v.w * r * wv.w;
  ((float4*)(out + (size_t)b * DIM))[threadIdx.x] = o;
}

// ---- LDS-transpose block reduce: 256 threads, 8 accumulators/thread ----
// After call, threads with (tid&31)==0 hold total for batch bb=tid>>5 in *res.
__device__ __forceinline__ float block_reduce8(const float acc[8], float* lds,
                                               int* bb_out) {
  int tid = threadIdx.x;
#pragma unroll
  for (int b = 0; b < 8; ++b) lds[tid * 9 + b] = acc[b];
  __syncthreads();
  int bb = tid >> 5, i = tid & 31;
  float s = 0.0f;
#pragma unroll
  for (int j = 0; j < 8; ++j) s += lds[(i + 32 * j) * 9 + bb];
#pragma unroll
  for (int o = 16; o; o >>= 1) s += __shfl_xor(s, o);
  *bb_out = bb;
  return s;   // valid on lanes with (tid&31)==0
}

// -------------------- QKV GEMV: one block per output row (3072 rows) --------------------
__global__ void qkv_k(const float* __restrict__ h,
                      const float* __restrict__ wq, const float* __restrict__ wk,
                      const float* __restrict__ wv,
                      float* __restrict__ q, float* __restrict__ k, float* __restrict__ v) {
  __shared__ float lds[256 * 9];
  int row = blockIdx.x;                  // 0..3071
  int mat = row >> 10, r = row & 1023;
  const float* W = (mat == 0 ? wq : mat == 1 ? wk : wv) + (size_t)r * DIM;
  int tid = threadIdx.x;
  float4 w4 = *(const float4*)(W + tid * 4);
  float acc[8];
#pragma unroll
  for (int bb = 0; bb < 8; ++bb) {
    float4 h4 = *(const float4*)(h + bb * DIM + tid * 4);
    acc[bb] = w4.x * h4.x + w4.y * h4.y + w4.z * h4.z + w4.w * h4.w;
  }
  int bb; float s = block_reduce8(acc, lds, &bb);
  if ((tid & 31) == 0) {
    float* dst = (mat == 0 ? q : mat == 1 ? k : v);
    dst[bb * DIM + r] = s;
  }
}

// -------------------- o-proj GEMV + residual: one block per row --------------------
__global__ void proj_res_k(const float* __restrict__ in, const float* __restrict__ W0,
                           const float* __restrict__ resid, float* __restrict__ out) {
  __shared__ float lds[256 * 9];
  int r = blockIdx.x;                    // 0..1023
  int tid = threadIdx.x;
  float4 w4 = *(const float4*)(W0 + (size_t)r * DIM + tid * 4);
  float acc[8];
#pragma unroll
  for (int bb = 0; bb < 8; ++bb) {
    float4 h4 = *(const float4*)(in + bb * DIM + tid * 4);
    acc[bb] = w4.x * h4.x + w4.y * h4.y + w4.z * h4.z + w4.w * h4.w;
  }
  int bb; float s = block_reduce8(acc, lds, &bb);
  if ((tid & 31) == 0) out[bb * DIM + r] = s + resid[bb * DIM + r];
}

// -------------------- FFN w1/w3 + SwiGLU: one block per row (4096 rows) --------------------
__global__ void ffn13_k(const float* __restrict__ h, const float* __restrict__ w1,
                        const float* __restrict__ w3, float* __restrict__ g) {
  __shared__ float ldsA[256 * 9];
  __shared__ float ldsC[256 * 9];
  int r = blockIdx.x;                    // 0..4095
  int tid = threadIdx.x;
  float4 w14 = *(const float4*)(w1 + (size_t)r * DIM + tid * 4);
  float4 w34 = *(const float4*)(w3 + (size_t)r * DIM + tid * 4);
  float a[8], c[8];
#pragma unroll
  for (int bb = 0; bb < 8; ++bb) {
    float4 h4 = *(const float4*)(h + bb * DIM + tid * 4);
    a[bb] = w14.x * h4.x + w14.y * h4.y + w14.z * h4.z + w14.w * h4.w;
    c[bb] = w34.x * h4.x + w34.y * h4.y + w34.z * h4.z + w34.w * h4.w;
  }
#pragma unroll
  for (int b = 0; b < 8; ++b) { ldsA[tid * 9 + b] = a[b]; ldsC[tid * 9 + b] = c[b]; }
  __syncthreads();
  int bb = tid >> 5, i = tid & 31;
  float sa = 0.0f, sc = 0.0f;
#pragma unroll
  for (int j = 0; j < 8; ++j) {
    sa += ldsA[(i + 32 * j) * 9 + bb];
    sc += ldsC[(i + 32 * j) * 9 + bb];
  }
#pragma unroll
  for (int o = 16; o; o >>= 1) { sa += __shfl_xor(sa, o); sc += __shfl_xor(sc, o); }
  if (i == 0) {
    float sv = sa / (1.0f + __expf(-sa));   // silu
    g[bb * 4 * DIM + r] = sv * sc;
  }
}

// -------------------- FFN w2 partial: grid (1024 rows, 4 K-splits) --------------------
__global__ void ffn2_part_k(const float* __restrict__ g, const float* __restrict__ w2,
                            float* __restrict__ part) {
  __shared__ float lds[256 * 9];
  int r = blockIdx.x;                    // 0..1023
  int ks = blockIdx.y;                   // 0..3
  int tid = threadIdx.x;
  int j = ks * 1024 + tid * 4;
  float4 w4 = *(const float4*)(w2 + (size_t)r * 4 * DIM + j);
  float acc[8];
#pragma unroll
  for (int bb = 0; bb < 8; ++bb) {
    float4 g4 = *(const float4*)(g + bb * 4 * DIM + j);
    acc[bb] = w4.x * g4.x + w4.y * g4.y + w4.z * g4.z + w4.w * g4.w;
  }
  int bb; float s = block_reduce8(acc, lds, &bb);
  if ((tid & 31) == 0) part[(ks * 8 + bb) * DIM + r] = s;
}

__global__ void ffn2_red_k(const float* __restrict__ part, const float* __restrict__ resid,
                           float* __restrict__ out) {
  int idx = blockIdx.x * 256 + threadIdx.x;   // 0..8191
  int bb = idx >> 10, r = idx & 1023;
  float s = resid[idx];
#pragma unroll
  for (int ks = 0; ks < 4; ++ks) s += part[(ks * 8 + bb) * DIM + r];
  out[idx] = s;
}

// -------------------- flash-decode partial: grid (NSPLIT, B*H), 8 half-wave groups --------------------
__global__ void attn_partial_k(const float* __restrict__ qb, const float* __restrict__ kb,
                               const float* __restrict__ vb,
                               const float* __restrict__ kheap, const float* __restrict__ vheap,
                               const int* __restrict__ bt, const int* __restrict__ ctx_lens,
                               float* __restrict__ pm, float* __restrict__ ps,
                               float* __restrict__ pacc) {
  int c  = blockIdx.x;
  int bh = blockIdx.y;
  int b = bh >> 3, hh = bh & 7;
  int grp = threadIdx.x >> 5, lane = threadIdx.x & 31;
  int ctx = ctx_lens[b];
  int CH = (ctx + NSPLIT - 1) / NSPLIT;
  int t0 = c * CH;
  int t1 = t0 + CH; if (t1 > ctx) t1 = ctx;
  int last = ctx - 1;
  const float4 q4 = *(const float4*)(qb + (size_t)b * DIM + hh * HD + lane * 4);
  const int* btb = bt + b * NB;
  float m = -1e30f, ssum = 0.0f;
  float4 acc = make_float4(0.f, 0.f, 0.f, 0.f);
  for (int t = t0 + grp; t < t1; t += 8) {
    const float *Kp, *Vp;
    if (t == last) {
      Kp = kb + (size_t)b * DIM + hh * HD;
      Vp = vb + (size_t)b * DIM + hh * HD;
    } else {
      int pb = btb[t >> 4];
      size_t base = ((((size_t)pb * BS) + (t & 15)) * NH + hh) * HD;
      Kp = kheap + base;
      Vp = vheap + base;
    }
    float4 k4 = *(const float4*)(Kp + lane * 4);
    float sc = q4.x * k4.x + q4.y * k4.y + q4.z * k4.z + q4.w * k4.w;
#pragma unroll
    for (int o = 16; o; o >>= 1) sc += __shfl_xor(sc, o);
    sc *= SCALE;
    float mnew = fmaxf(m, sc);
    float f = __expf(m - mnew);
    float p = __expf(sc - mnew);
    float4 v4 = *(const float4*)(Vp + lane * 4);
    ssum = ssum * f + p;
    acc.x = acc.x * f + p * v4.x;
    acc.y = acc.y * f + p * v4.y;
    acc.z = acc.z * f + p * v4.z;
    acc.w = acc.w * f + p * v4.w;
    m = mnew;
  }
  int pi = bh * (NSPLIT * 8) + c * 8 + grp;
  if (lane == 0) { pm[pi] = m; ps[pi] = ssum; }
  *(float4*)(pacc + (size_t)pi * HD + lane * 4) = acc;
}

// -------------------- flash-decode reduce: one block per (b,h), 128 threads --------------------
__global__ void attn_reduce_k(const float* __restrict__ pm, const float* __restrict__ ps,
                              const float* __restrict__ pacc, float* __restrict__ ab) {
  int bh = blockIdx.x;
  int tid = threadIdx.x;   // 0..127
  __shared__ float f[128];
  __shared__ float red[128];
  float mi = pm[bh * 128 + tid];
  red[tid] = mi; __syncthreads();
#pragma unroll
  for (int o = 64; o; o >>= 1) {
    if (tid < o) red[tid] = fmaxf(red[tid], red[tid + o]);
    __syncthreads();
  }
  float M = red[0];
  __syncthreads();
  float fi = __expf(mi - M);
  f[tid] = fi;
  red[tid] = ps[bh * 128 + tid] * fi;
  __syncthreads();
#pragma unroll
  for (int o = 64; o; o >>= 1) {
    if (tid < o) red[tid] += red[tid + o];
    __syncthreads();
  }
  float inv = 1.0f / red[0];
  float od = 0.0f;
  for (int p = 0; p < 128; ++p)
    od += pacc[((size_t)bh * 128 + p) * HD + tid] * f[p];
  ab[bh * HD + tid] = od * inv;
}

extern "C" void kernel_launch(void* const* d_in, const int* in_sizes, int n_in,
                              void* d_out, int out_size, void* d_ws, size_t ws_size,
                              hipStream_t stream) {
  const float* x0    = (const float*)d_in[0];
  const float* kheap = (const float*)d_in[1];
  const float* vheap = (const float*)d_in[2];
  const int*   bt    = (const int*)d_in[3];
  // d_in[4] = slot_mapping (int64) — unused; derived from context_lens instead.
  const int*   ctx   = (const int*)d_in[5];
  const float* wq    = (const float*)d_in[6];
  const float* wk    = (const float*)d_in[7];
  const float* wv    = (const float*)d_in[8];
  const float* wo    = (const float*)d_in[9];
  const float* w1    = (const float*)d_in[10];
  const float* w2    = (const float*)d_in[11];
  const float* w3    = (const float*)d_in[12];
  const float* norm1 = (const float*)d_in[13];
  const float* norm2 = (const float*)d_in[14];
  const float* normf = (const float*)d_in[15];

  float* ws = (float*)d_ws;
  float* h    = ws;                 // 8192
  float* q    = ws + 8192;          // 8192
  float* k    = ws + 16384;         // 8192
  float* v    = ws + 24576;         // 8192
  float* g    = ws + 32768;         // 32768
  float* xa   = ws + 65536;         // 8192
  float* xf   = ws + 73728;         // 8192
  float* ab   = ws + 81920;         // 8192
  float* pm   = ws + 90112;         // 8192
  float* ps   = ws + 98304;         // 8192
  float* pacc = ws + 106496;        // 64*128*128 = 1048576 floats
  float* part = pacc;               // reuse: pacc dead once attn_reduce is done (32768 floats)

  const size_t WD = (size_t)DIM * DIM;       // 1 MiB floats
  const size_t WF = (size_t)4 * DIM * DIM;   // 4 MiB floats

  for (int l = 0; l < LL; ++l) {
    const float* xin = (l == 0) ? x0 : xf;
    rmsnorm_k<<<BB, 256, 0, stream>>>(xin, norm1 + l * DIM, h);
    qkv_k<<<3072, 256, 0, stream>>>(h, wq + l * WD, wk + l * WD, wv + l * WD, q, k, v);
    attn_partial_k<<<dim3(NSPLIT, BB * NH), 256, 0, stream>>>(
        q, k, v, kheap, vheap, bt + l * BB * NB, ctx, pm, ps, pacc);
    attn_reduce_k<<<BB * NH, 128, 0, stream>>>(pm, ps, pacc, ab);
    proj_res_k<<<1024, 256, 0, stream>>>(ab, wo + l * WD, xin, xa);
    rmsnorm_k<<<BB, 256, 0, stream>>>(xa, norm2 + l * DIM, h);
    ffn13_k<<<4096, 256, 0, stream>>>(h, w1 + l * WF, w3 + l * WF, g);
    ffn2_part_k<<<dim3(1024, 4), 256, 0, stream>>>(g, w2 + l * WF, part);
    ffn2_red_k<<<32, 256, 0, stream>>>(part, xa, xf);
  }
  rmsnorm_k<<<BB, 256, 0, stream>>>(xf, normf, (float*)d_out);
}

// Round 3
// 155.094 us; speedup vs baseline: 2.2633x; 1.1743x over previous
//
#include <hip/hip_runtime.h>

#define BB    8
#define LL    2
#define DIM   1024
#define NH    8
#define HD    128
#define BS    16
#define NB    129
#define NSPLIT 32
#define SCALE 0.08838834764831845f   // 1/sqrt(128)
#define EPS   1e-5f

// -------------------- final RMSNorm: one block per batch row --------------------
__global__ void rmsnorm_k(const float* __restrict__ x, const float* __restrict__ w,
                          float* __restrict__ out) {
  int b = blockIdx.x;
  float4 v = ((const float4*)(x + (size_t)b * DIM))[threadIdx.x];
  float s = v.x * v.x + v.y * v.y + v.z * v.z + v.w * v.w;
#pragma unroll
  for (int o = 32; o; o >>= 1) s += __shfl_xor(s, o);
  __shared__ float wsum[4];
  int wid = threadIdx.x >> 6;
  if ((threadIdx.x & 63) == 0) wsum[wid] = s;
  __syncthreads();
  float tot = wsum[0] + wsum[1] + wsum[2] + wsum[3];
  float r = rsqrtf(tot * (1.0f / DIM) + EPS);
  float4 wv = ((const float4*)w)[threadIdx.x];
  float4 o;
  o.x = v.x * r * wv.x; o.y = v.y * r * wv.y;
  o.z = v.z * r * wv.z; o.w = v.w * r * wv.w;
  ((float4*)(out + (size_t)b * DIM))[threadIdx.x] = o;
}

// ---- in-block rms scales: from 8 per-thread partials -> scale[8] in LDS ----
__device__ __forceinline__ void block_rms_scales(const float ss[8], float* lds,
                                                 float* scale) {
  int tid = threadIdx.x;
#pragma unroll
  for (int b = 0; b < 8; ++b) lds[tid * 9 + b] = ss[b];
  __syncthreads();
  int bb = tid >> 5, i = tid & 31;
  float s = 0.0f;
#pragma unroll
  for (int j = 0; j < 8; ++j) s += lds[(i + 32 * j) * 9 + bb];
#pragma unroll
  for (int o = 16; o; o >>= 1) s += __shfl_xor(s, o);
  if (i == 0) scale[bb] = rsqrtf(s * (1.0f / DIM) + EPS);
  __syncthreads();   // scale ready; lds reusable after this point
}

// ---- LDS-transpose block reduce of 8 accumulators ----
__device__ __forceinline__ float block_reduce8(const float acc[8], float* lds,
                                               int* bb_out) {
  int tid = threadIdx.x;
#pragma unroll
  for (int b = 0; b < 8; ++b) lds[tid * 9 + b] = acc[b];
  __syncthreads();
  int bb = tid >> 5, i = tid & 31;
  float s = 0.0f;
#pragma unroll
  for (int j = 0; j < 8; ++j) s += lds[(i + 32 * j) * 9 + bb];
#pragma unroll
  for (int o = 16; o; o >>= 1) s += __shfl_xor(s, o);
  *bb_out = bb;
  return s;   // valid on lanes with (tid&31)==0
}

// ------ QKV GEMV with fused RMSNorm: one block per output row (3072 rows) ------
__global__ void qkv_k(const float* __restrict__ x, const float* __restrict__ nw,
                      const float* __restrict__ wq, const float* __restrict__ wk,
                      const float* __restrict__ wv,
                      float* __restrict__ q, float* __restrict__ k, float* __restrict__ v) {
  __shared__ float lds[256 * 9];
  __shared__ float scale[8];
  int tid = threadIdx.x;
  float4 xr[8];
  float ss[8];
#pragma unroll
  for (int bb = 0; bb < 8; ++bb) {
    xr[bb] = *(const float4*)(x + bb * DIM + tid * 4);
    ss[bb] = xr[bb].x * xr[bb].x + xr[bb].y * xr[bb].y +
             xr[bb].z * xr[bb].z + xr[bb].w * xr[bb].w;
  }
  block_rms_scales(ss, lds, scale);

  int row = blockIdx.x;                  // 0..3071
  int mat = row >> 10, r = row & 1023;
  const float* W = (mat == 0 ? wq : mat == 1 ? wk : wv) + (size_t)r * DIM;
  float4 wn = *(const float4*)(nw + tid * 4);
  float4 w4 = *(const float4*)(W + tid * 4);
  float acc[8];
#pragma unroll
  for (int bb = 0; bb < 8; ++bb) {
    acc[bb] = w4.x * (xr[bb].x * wn.x) + w4.y * (xr[bb].y * wn.y) +
              w4.z * (xr[bb].z * wn.z) + w4.w * (xr[bb].w * wn.w);
  }
  int bb; float s = block_reduce8(acc, lds, &bb);
  if ((tid & 31) == 0) {
    float* dst = (mat == 0 ? q : mat == 1 ? k : v);
    dst[bb * DIM + r] = s * scale[bb];
  }
}

// -------------------- o-proj GEMV + residual: one block per row --------------------
__global__ void proj_res_k(const float* __restrict__ in, const float* __restrict__ W0,
                           const float* __restrict__ resid, float* __restrict__ out) {
  __shared__ float lds[256 * 9];
  int r = blockIdx.x;                    // 0..1023
  int tid = threadIdx.x;
  float4 w4 = *(const float4*)(W0 + (size_t)r * DIM + tid * 4);
  float acc[8];
#pragma unroll
  for (int bb = 0; bb < 8; ++bb) {
    float4 h4 = *(const float4*)(in + bb * DIM + tid * 4);
    acc[bb] = w4.x * h4.x + w4.y * h4.y + w4.z * h4.z + w4.w * h4.w;
  }
  int bb; float s = block_reduce8(acc, lds, &bb);
  if ((tid & 31) == 0) out[bb * DIM + r] = s + resid[bb * DIM + r];
}

// ------ FFN w1/w3 + SwiGLU with fused RMSNorm: one block per row (4096 rows) ------
__global__ void ffn13_k(const float* __restrict__ xa, const float* __restrict__ nw,
                        const float* __restrict__ w1, const float* __restrict__ w3,
                        float* __restrict__ g) {
  __shared__ float ldsA[256 * 9];
  __shared__ float ldsC[256 * 9];
  __shared__ float scale[8];
  int tid = threadIdx.x;
  float4 xr[8];
  float ss[8];
#pragma unroll
  for (int bb = 0; bb < 8; ++bb) {
    xr[bb] = *(const float4*)(xa + bb * DIM + tid * 4);
    ss[bb] = xr[bb].x * xr[bb].x + xr[bb].y * xr[bb].y +
             xr[bb].z * xr[bb].z + xr[bb].w * xr[bb].w;
  }
  block_rms_scales(ss, ldsA, scale);

  int r = blockIdx.x;                    // 0..4095
  float4 wn = *(const float4*)(nw + tid * 4);
  float4 w14 = *(const float4*)(w1 + (size_t)r * DIM + tid * 4);
  float4 w34 = *(const float4*)(w3 + (size_t)r * DIM + tid * 4);
  float a[8], c[8];
#pragma unroll
  for (int bb = 0; bb < 8; ++bb) {
    float hx = xr[bb].x * wn.x, hy = xr[bb].y * wn.y;
    float hz = xr[bb].z * wn.z, hw = xr[bb].w * wn.w;
    a[bb] = w14.x * hx + w14.y * hy + w14.z * hz + w14.w * hw;
    c[bb] = w34.x * hx + w34.y * hy + w34.z * hz + w34.w * hw;
  }
#pragma unroll
  for (int b = 0; b < 8; ++b) { ldsA[tid * 9 + b] = a[b]; ldsC[tid * 9 + b] = c[b]; }
  __syncthreads();
  int bb = tid >> 5, i = tid & 31;
  float sa = 0.0f, sc = 0.0f;
#pragma unroll
  for (int j = 0; j < 8; ++j) {
    sa += ldsA[(i + 32 * j) * 9 + bb];
    sc += ldsC[(i + 32 * j) * 9 + bb];
  }
#pragma unroll
  for (int o = 16; o; o >>= 1) { sa += __shfl_xor(sa, o); sc += __shfl_xor(sc, o); }
  if (i == 0) {
    float sv = (sa * scale[bb]);
    sv = sv / (1.0f + __expf(-sv));      // silu
    g[bb * 4 * DIM + r] = sv * (sc * scale[bb]);
  }
}

// ------ FFN w2 + residual, single pass (K=4096): one block per row ------
__global__ void ffn2_k(const float* __restrict__ g, const float* __restrict__ w2,
                       const float* __restrict__ resid, float* __restrict__ out) {
  __shared__ float lds[256 * 9];
  int r = blockIdx.x;                    // 0..1023
  int tid = threadIdx.x;
  const float* W = w2 + (size_t)r * 4 * DIM;
  float acc[8] = {};
#pragma unroll
  for (int j4 = 0; j4 < 4; ++j4) {
    int j = j4 * 1024 + tid * 4;
    float4 w4 = *(const float4*)(W + j);
#pragma unroll
    for (int bb = 0; bb < 8; ++bb) {
      float4 g4 = *(const float4*)(g + bb * 4 * DIM + j);
      acc[bb] += w4.x * g4.x + w4.y * g4.y + w4.z * g4.z + w4.w * g4.w;
    }
  }
  int bb; float s = block_reduce8(acc, lds, &bb);
  if ((tid & 31) == 0) out[bb * DIM + r] = s + resid[bb * DIM + r];
}

// ------ flash-decode partial: grid (NSPLIT, B*H), 8 half-wave groups ------
__global__ void attn_partial_k(const float* __restrict__ qb, const float* __restrict__ kb,
                               const float* __restrict__ vb,
                               const float* __restrict__ kheap, const float* __restrict__ vheap,
                               const int* __restrict__ bt, const int* __restrict__ ctx_lens,
                               float* __restrict__ pm, float* __restrict__ ps,
                               float* __restrict__ pacc) {
  int c  = blockIdx.x;
  int bh = blockIdx.y;
  int b = bh >> 3, hh = bh & 7;
  int grp = threadIdx.x >> 5, lane = threadIdx.x & 31;
  int ctx = ctx_lens[b];
  int CH = (ctx + NSPLIT - 1) / NSPLIT;
  int t0 = c * CH;
  int t1 = t0 + CH; if (t1 > ctx) t1 = ctx;
  int last = ctx - 1;
  const float4 q4 = *(const float4*)(qb + (size_t)b * DIM + hh * HD + lane * 4);
  const int* btb = bt + b * NB;
  float m = -1e30f, ssum = 0.0f;
  float4 acc = make_float4(0.f, 0.f, 0.f, 0.f);
  for (int t = t0 + grp; t < t1; t += 8) {
    const float *Kp, *Vp;
    if (t == last) {
      Kp = kb + (size_t)b * DIM + hh * HD;
      Vp = vb + (size_t)b * DIM + hh * HD;
    } else {
      int pb = btb[t >> 4];
      size_t base = ((((size_t)pb * BS) + (t & 15)) * NH + hh) * HD;
      Kp = kheap + base;
      Vp = vheap + base;
    }
    float4 k4 = *(const float4*)(Kp + lane * 4);
    float sc = q4.x * k4.x + q4.y * k4.y + q4.z * k4.z + q4.w * k4.w;
#pragma unroll
    for (int o = 16; o; o >>= 1) sc += __shfl_xor(sc, o);
    sc *= SCALE;
    float mnew = fmaxf(m, sc);
    float f = __expf(m - mnew);
    float p = __expf(sc - mnew);
    float4 v4 = *(const float4*)(Vp + lane * 4);
    ssum = ssum * f + p;
    acc.x = acc.x * f + p * v4.x;
    acc.y = acc.y * f + p * v4.y;
    acc.z = acc.z * f + p * v4.z;
    acc.w = acc.w * f + p * v4.w;
    m = mnew;
  }
  int pi = bh * (NSPLIT * 8) + c * 8 + grp;
  if (lane == 0) { pm[pi] = m; ps[pi] = ssum; }
  *(float4*)(pacc + (size_t)pi * HD + lane * 4) = acc;
}

// ------ flash-decode reduce: one block per (b,h), 128 threads, 256 partials ------
__global__ void attn_reduce_k(const float* __restrict__ pm, const float* __restrict__ ps,
                              const float* __restrict__ pacc, float* __restrict__ ab) {
  int bh = blockIdx.x;
  int tid = threadIdx.x;   // 0..127
  __shared__ float f[256];
  __shared__ float red[128];
  float m1 = pm[bh * 256 + tid];
  float m2 = pm[bh * 256 + 128 + tid];
  red[tid] = fmaxf(m1, m2); __syncthreads();
#pragma unroll
  for (int o = 64; o; o >>= 1) {
    if (tid < o) red[tid] = fmaxf(red[tid], red[tid + o]);
    __syncthreads();
  }
  float M = red[0];
  __syncthreads();
  float f1 = __expf(m1 - M), f2 = __expf(m2 - M);
  f[tid] = f1; f[tid + 128] = f2;
  red[tid] = ps[bh * 256 + tid] * f1 + ps[bh * 256 + 128 + tid] * f2;
  __syncthreads();
#pragma unroll
  for (int o = 64; o; o >>= 1) {
    if (tid < o) red[tid] += red[tid + o];
    __syncthreads();
  }
  float inv = 1.0f / red[0];
  float od = 0.0f;
  for (int p = 0; p < 256; ++p)
    od += pacc[((size_t)bh * 256 + p) * HD + tid] * f[p];
  ab[bh * HD + tid] = od * inv;
}

extern "C" void kernel_launch(void* const* d_in, const int* in_sizes, int n_in,
                              void* d_out, int out_size, void* d_ws, size_t ws_size,
                              hipStream_t stream) {
  const float* x0    = (const float*)d_in[0];
  const float* kheap = (const float*)d_in[1];
  const float* vheap = (const float*)d_in[2];
  const int*   bt    = (const int*)d_in[3];
  // d_in[4] = slot_mapping (int64) — unused; derived from context_lens instead.
  const int*   ctx   = (const int*)d_in[5];
  const float* wq    = (const float*)d_in[6];
  const float* wk    = (const float*)d_in[7];
  const float* wv    = (const float*)d_in[8];
  const float* wo    = (const float*)d_in[9];
  const float* w1    = (const float*)d_in[10];
  const float* w2    = (const float*)d_in[11];
  const float* w3    = (const float*)d_in[12];
  const float* norm1 = (const float*)d_in[13];
  const float* norm2 = (const float*)d_in[14];
  const float* normf = (const float*)d_in[15];

  float* ws = (float*)d_ws;
  float* q    = ws;                 // 8192
  float* k    = ws + 8192;          // 8192
  float* v    = ws + 16384;         // 8192
  float* g    = ws + 24576;         // 32768
  float* xa   = ws + 57344;         // 8192
  float* xf   = ws + 65536;         // 8192
  float* ab   = ws + 73728;         // 8192
  float* pm   = ws + 81920;         // 64*256 = 16384
  float* ps   = ws + 98304;         // 16384
  float* pacc = ws + 114688;        // 64*256*128 = 2097152 floats (8 MB)

  const size_t WD = (size_t)DIM * DIM;       // 1 MiB floats
  const size_t WF = (size_t)4 * DIM * DIM;   // 4 MiB floats

  for (int l = 0; l < LL; ++l) {
    const float* xin = (l == 0) ? x0 : xf;
    qkv_k<<<3072, 256, 0, stream>>>(xin, norm1 + l * DIM,
                                    wq + l * WD, wk + l * WD, wv + l * WD, q, k, v);
    attn_partial_k<<<dim3(NSPLIT, BB * NH), 256, 0, stream>>>(
        q, k, v, kheap, vheap, bt + l * BB * NB, ctx, pm, ps, pacc);
    attn_reduce_k<<<BB * NH, 128, 0, stream>>>(pm, ps, pacc, ab);
    proj_res_k<<<1024, 256, 0, stream>>>(ab, wo + l * WD, xin, xa);
    ffn13_k<<<4096, 256, 0, stream>>>(xa, norm2 + l * DIM, w1 + l * WF, w3 + l * WF, g);
    ffn2_k<<<1024, 256, 0, stream>>>(g, w2 + l * WF, xa, xf);
  }
  rmsnorm_k<<<BB, 256, 0, stream>>>(xf, normf, (float*)d_out);
}